// Round 10
// baseline (228.014 us; speedup 1.0000x reference)
//
#include <hip/hip_runtime.h>
#include <stdint.h>

// VectorQuantizer — f32 I/O confirmed. d_in[0]=z [16384,64], d_in[1]=e [8192,64];
// d_out f32: [z_q 16384*64][idx-as-float 16384]. d_ws >= 16MB confirmed.
//
// FROZEN exact numerics (eval path only):
//   sz,se: scalar pairwise-8; c: 4 lanes (k mod 4), mul/add separately rounded,
//   16-chunks ascending, reversed sub-blocks (+12,+8,+4,+0), hadd (q0+q1)+(q2+q3);
//   A=fl(sz+se); d=fl(A-2c); argmin strict-<, first (smallest) index wins.
//
// Round-10: INVERTED rescore. Round-9's wave-per-row rescore was latency-bound
// (Occ 12%, VALU 21%: ~205 evals/wave vs ~2K cyc fixed overhead). Now:
// select builds per-chunk row lists (lane-spread atomics, cap 16384 = provably
// no overflow); eval: block=(chunk, j-half), thread=row -> e-rows wave-uniform
// s_loads (round-4-proven), z in VGPRs with __launch_bounds__(128,2) so the
// allocator gets a 256-reg budget (the recurring remat disease). Combine via
// round-7-verified atomicMin(packed = d_bits<<32 | j): deterministic, first-
// index ties preserved.

#define NROWS 16384
#define NE    8192
#define D     64
#define BN    128
#define NCH   (NE / BN)     // 64
#define BAND  1.25e-4f
#define CAND_CAP 16384
#define EVB   16            // eval grid-stride blocks per (chunk, half)

typedef __attribute__((ext_vector_type(8))) short short8;
typedef __attribute__((ext_vector_type(4))) float f32x4;

// ---------- frozen exact helpers ----------
__device__ __forceinline__ float sumsq_pairwise8(const float* x) {
    float r8[8];
    #pragma unroll
    for (int l = 0; l < 8; ++l) r8[l] = __fmul_rn(x[l], x[l]);
    #pragma unroll
    for (int i = 8; i < 64; i += 8)
        #pragma unroll
        for (int l = 0; l < 8; ++l)
            r8[l] = __fadd_rn(r8[l], __fmul_rn(x[i + l], x[i + l]));
    return __fadd_rn(__fadd_rn(__fadd_rn(r8[0], r8[1]), __fadd_rn(r8[2], r8[3])),
                     __fadd_rn(__fadd_rn(r8[4], r8[5]), __fadd_rn(r8[6], r8[7])));
}

__device__ __forceinline__ uint32_t bf16rn(float f) {
    union { float f; uint32_t u; } c; c.f = f;
    return (c.u + 0x7FFFu + ((c.u >> 16) & 1u)) >> 16;
}
__device__ __forceinline__ uint32_t pk2(float lo, float hi) {
    return bf16rn(lo) | (bf16rn(hi) << 16);
}

// ---------- phase 0a: f32 -> bf16 (RN) ----------
__global__ __launch_bounds__(256)
void vq_convert(const float* __restrict__ z, const float* __restrict__ e,
                uint32_t* __restrict__ zb, uint32_t* __restrict__ eb)
{
    const int i = blockIdx.x * 256 + threadIdx.x;
    const int nz = NROWS * D / 8;
    const int ne = NE * D / 8;
    if (i < nz) {
        const float4 a = ((const float4*)z)[i * 2];
        const float4 b = ((const float4*)z)[i * 2 + 1];
        uint4 o; o.x = pk2(a.x, a.y); o.y = pk2(a.z, a.w);
        o.z = pk2(b.x, b.y); o.w = pk2(b.z, b.w);
        ((uint4*)zb)[i] = o;
    } else if (i < nz + ne) {
        const int k = i - nz;
        const float4 a = ((const float4*)e)[k * 2];
        const float4 b = ((const float4*)e)[k * 2 + 1];
        uint4 o; o.x = pk2(a.x, a.y); o.y = pk2(a.z, a.w);
        o.z = pk2(b.x, b.y); o.w = pk2(b.z, b.w);
        ((uint4*)eb)[k] = o;
    }
}

// ---------- phase 0b: exact sz[row], se[j]; zero chunk counters ----------
__global__ __launch_bounds__(256)
void vq_prep(const float* __restrict__ z, const float* __restrict__ e,
             float* __restrict__ sz_arr, float* __restrict__ se_arr,
             unsigned int* __restrict__ counts)
{
    const int i = blockIdx.x * 256 + threadIdx.x;
    if (i < NCH) counts[i] = 0u;
    const float* p;
    float* dst;
    if (i < NROWS) { p = z + (size_t)i * D; dst = sz_arr + i; }
    else if (i < NROWS + NE) { p = e + (size_t)(i - NROWS) * D; dst = se_arr + (i - NROWS); }
    else return;
    float x[D];
    #pragma unroll
    for (int k = 0; k < D; k += 4) {
        const float4 v = *(const float4*)(p + k);
        x[k] = v.x; x[k + 1] = v.y; x[k + 2] = v.z; x[k + 3] = v.w;
    }
    *dst = sumsq_pairwise8(x);
}

// ---------- phase 1: MFMA GEMM + per-(row,chunk) max (verified, unchanged) ----------
__global__ __launch_bounds__(256)
void vq_scan_mfma(const uint16_t* __restrict__ zb, const uint16_t* __restrict__ eb,
                  float* __restrict__ cmax)
{
    __shared__ uint16_t elds[BN][72];
    __shared__ float    rmld[4][64][20];

    const int tid  = threadIdx.x;
    const int lane = tid & 63, w = tid >> 6;
    const int mb   = blockIdx.x >> 5;
    const int jb   = blockIdx.x & 31;
    const int row0 = mb * 256 + w * 64;
    const int l15  = lane & 15, l4 = lane >> 4;

    short8 af[4][2];
    #pragma unroll
    for (int m = 0; m < 4; ++m)
        #pragma unroll
        for (int h = 0; h < 2; ++h)
            af[m][h] = *(const short8*)(zb + (size_t)(row0 + m * 16 + l15) * D + h * 32 + l4 * 8);

    const f32x4 z4 = {0.f, 0.f, 0.f, 0.f};

    #pragma unroll 1
    for (int c = 0; c < 2; ++c) {
        const int j0 = jb * 256 + c * BN;
        {
            const int srow = tid >> 1, shalf = tid & 1;
            const uint16_t* sp = eb + (size_t)(j0 + srow) * D + shalf * 32;
            uint16_t* dp = &elds[srow][shalf * 32];
            #pragma unroll
            for (int q = 0; q < 4; ++q)
                *(short8*)(dp + q * 8) = *(const short8*)(sp + q * 8);
        }
        __syncthreads();

        f32x4 rm[4];
        #pragma unroll
        for (int m = 0; m < 4; ++m) rm[m] = {-3.0e38f, -3.0e38f, -3.0e38f, -3.0e38f};

        #pragma unroll 1
        for (int n = 0; n < 8; ++n) {
            const uint16_t* bp = &elds[n * 16 + l15][l4 * 8];
            const short8 b0 = *(const short8*)(bp);
            const short8 b1 = *(const short8*)(bp + 32);
            #pragma unroll
            for (int m = 0; m < 4; ++m) {
                f32x4 acc = __builtin_amdgcn_mfma_f32_16x16x32_bf16(af[m][0], b0, z4, 0, 0, 0);
                acc = __builtin_amdgcn_mfma_f32_16x16x32_bf16(af[m][1], b1, acc, 0, 0, 0);
                #pragma unroll
                for (int r = 0; r < 4; ++r) rm[m][r] = fmaxf(rm[m][r], acc[r]);
            }
        }

        #pragma unroll
        for (int m = 0; m < 4; ++m)
            *(f32x4*)&rmld[w][lane][m * 4] = rm[m];
        const int r  = lane;
        const int mm = r >> 4, rg = r & 3, lg = ((r & 15) >> 2) * 16;
        float v = rmld[w][lg][mm * 4 + rg];
        #pragma unroll
        for (int i = 1; i < 16; ++i) v = fmaxf(v, rmld[w][lg + i][mm * 4 + rg]);
        cmax[(size_t)(row0 + r) * NCH + (jb * 2 + c)] = v;
        __syncthreads();
    }
}

// ---------- phase 2a: band-select -> per-chunk inverted row lists ----------
__global__ __launch_bounds__(256)
void vq_select(const float* __restrict__ cmax, unsigned int* __restrict__ counts,
               int* __restrict__ cand, unsigned long long* __restrict__ packed)
{
    const int lane = threadIdx.x & 63, w = threadIdx.x >> 6;
    const int row = blockIdx.x * 4 + w;

    const float ci = cmax[(size_t)row * NCH + lane];   // lane = chunk
    float cm = ci;
    #pragma unroll
    for (int o = 1; o < 64; o <<= 1) cm = fmaxf(cm, __shfl_xor(cm, o, 64));

    if (lane == 0) packed[row] = 0xFFFFFFFFFFFFFFFFull;

    if (ci >= cm - BAND) {
        const unsigned int slot = atomicAdd(&counts[lane], 1u);  // 64-way spread
        cand[(size_t)lane * CAND_CAP + slot] = row;              // slot < 16384 always
    }
}

// ---------- phase 2b: inverted exact eval: block=(chunk,half), thread=row ----------
__global__ __launch_bounds__(128, 2)
void vq_eval(const float* __restrict__ z, const float* __restrict__ e,
             const float* __restrict__ sz_arr, const float* __restrict__ se_arr,
             const unsigned int* __restrict__ counts, const int* __restrict__ cand,
             unsigned long long* __restrict__ packed)
{
    const int ch = blockIdx.x;           // 0..63
    const int jh = blockIdx.y;           // 0..1
    const int bb = blockIdx.z;           // 0..EVB-1
    const int t  = threadIdx.x;
    const unsigned int cnt = counts[ch];
    const int jbase = ch * BN + jh * 64;

    for (unsigned int s = bb * 128u + t; s < cnt; s += EVB * 128u) {
        const int row = cand[(size_t)ch * CAND_CAP + s];

        // z row in VGPRs (launch_bounds(128,2) -> 256-reg budget, no remat)
        float zr[D];
        {
            const float* zp = z + (size_t)row * D;
            #pragma unroll
            for (int k = 0; k < D; k += 4) {
                const float4 v = *(const float4*)(zp + k);
                zr[k] = v.x; zr[k + 1] = v.y; zr[k + 2] = v.z; zr[k + 3] = v.w;
            }
        }
        const float sz = sz_arr[row];

        float bd = 3.0e38f; int bj = 0;
        #pragma unroll 1
        for (int jj = 0; jj < 64; ++jj) {
            const int j = jbase + jj;
            const float* er = e + (size_t)j * D;   // wave-uniform -> s_loads

            // frozen order: cc ascending; granules +12,+8,+4,+0; q_i gets k===i mod 4
            float q0 = 0.f, q1 = 0.f, q2 = 0.f, q3 = 0.f;
            #pragma unroll
            for (int cc = 0; cc < 4; ++cc) {
                #pragma unroll
                for (int sb = 3; sb >= 0; --sb) {
                    const int b = cc * 16 + sb * 4;
                    q0 = __fadd_rn(q0, __fmul_rn(zr[b + 0], er[b + 0]));
                    q1 = __fadd_rn(q1, __fmul_rn(zr[b + 1], er[b + 1]));
                    q2 = __fadd_rn(q2, __fmul_rn(zr[b + 2], er[b + 2]));
                    q3 = __fadd_rn(q3, __fmul_rn(zr[b + 3], er[b + 3]));
                }
            }
            const float c  = __fadd_rn(__fadd_rn(q0, q1), __fadd_rn(q2, q3));
            const float A  = __fadd_rn(sz, se_arr[j]);          // fl(sz + se)
            const float dd = __fsub_rn(A, __fadd_rn(c, c));     // fl(A - 2c)
            if (dd < bd) { bd = dd; bj = j; }                   // ascending j: first wins
        }
        // d > 0 always -> float bits monotone; min deterministic; low-32 j = tie-break
        const unsigned long long key =
            ((unsigned long long)__float_as_uint(bd) << 32) | (unsigned int)bj;
        atomicMin(packed + row, key);
    }
}

// ---------- phase 3: z_q + idx from packed (round-7-verified) ----------
__global__ __launch_bounds__(256)
void vq_zq(const float* __restrict__ z, const float* __restrict__ e,
           const unsigned long long* __restrict__ packed, float* __restrict__ out)
{
    const size_t m = (size_t)blockIdx.x * 256 + threadIdx.x;
    const int r = (int)(m >> 6), k = (int)(m & 63);
    const int sel = (int)(packed[r] & 0xFFFFFFFFull);
    const float zv = z[m];
    const float ev = e[(size_t)sel * D + k];
    out[m] = __fadd_rn(zv, __fsub_rn(ev, zv));
    if (k == 0) out[(size_t)NROWS * D + r] = (float)sel;
}

extern "C" void kernel_launch(void* const* d_in, const int* in_sizes, int n_in,
                              void* d_out, int out_size, void* d_ws, size_t ws_size,
                              hipStream_t stream)
{
    const float* z = (const float*)d_in[0];
    const float* e = (const float*)d_in[1];
    float* out = (float*)d_out;

    char* ws = (char*)d_ws;
    const size_t MB = 1024 * 1024, KB = 1024;
    uint16_t* zb               = (uint16_t*)(ws);                        // 0..2 MB
    uint16_t* eb               = (uint16_t*)(ws + 2 * MB);               // 2..3 MB
    float* cmaxb               = (float*)(ws + 3 * MB);                  // 3..7 MB
    float* sz_arr              = (float*)(ws + 7 * MB);                  // 64 KB
    float* se_arr              = (float*)(ws + 7 * MB + 64 * KB);        // 32 KB
    unsigned int* counts       = (unsigned int*)(ws + 7 * MB + 96 * KB); // 256 B
    unsigned long long* packed = (unsigned long long*)(ws + 7 * MB + 128 * KB); // 128 KB
    int* cand                  = (int*)(ws + 8 * MB);                    // 8..12 MB

    vq_convert  <<<dim3(768),                dim3(256), 0, stream>>>(z, e, (uint32_t*)zb, (uint32_t*)eb);
    vq_prep     <<<dim3((NROWS + NE) / 256), dim3(256), 0, stream>>>(z, e, sz_arr, se_arr, counts);
    vq_scan_mfma<<<dim3(2048),               dim3(256), 0, stream>>>(zb, eb, cmaxb);
    vq_select   <<<dim3(NROWS / 4),          dim3(256), 0, stream>>>(cmaxb, counts, cand, packed);
    vq_eval     <<<dim3(NCH, 2, EVB),        dim3(128), 0, stream>>>(z, e, sz_arr, se_arr, counts, cand, packed);
    vq_zq       <<<dim3(NROWS * D / 256),    dim3(256), 0, stream>>>(z, e, packed, out);
}

// Round 11
// 126.000 us; speedup vs baseline: 1.8096x; 1.8096x over previous
//
#include <hip/hip_runtime.h>
#include <stdint.h>

// VectorQuantizer — f32 I/O confirmed. d_in[0]=z [16384,64], d_in[1]=e [8192,64];
// d_out f32: [z_q 16384*64][idx-as-float 16384]. d_ws >= 16MB confirmed.
//
// FROZEN exact numerics (eval path only):
//   sz,se: scalar pairwise-8; c: 4 lanes (k mod 4), mul/add separately rounded,
//   16-chunks ascending, reversed sub-blocks (+12,+8,+4,+0), hadd (q0+q1)+(q2+q3);
//   A=fl(sz+se); d=fl(A-2c); argmin strict-<, first (smallest) index wins.
//
// Round-11: round-10's select burned 141us on ~26K contended device-scope
// atomicAdds to a 256-B counts[] (memory-side same-line serialization; VALUBusy
// 1%, WRITE_SIZE 2MB of dirtied lines). Replaced with atomic-free two-pass:
// select_mask (ballot -> per-row u64 mask, coalesced) + compact (block-per-chunk
// ordered prefix compaction). Eval (inverted, wave-uniform s_loads, 256-reg
// budget via __launch_bounds__(128,2)) + atomicMin combine unchanged (verified).

#define NROWS 16384
#define NE    8192
#define D     64
#define BN    128
#define NCH   (NE / BN)     // 64
#define BAND  1.25e-4f
#define CAND_CAP 16384
#define EVB   16

typedef __attribute__((ext_vector_type(8))) short short8;
typedef __attribute__((ext_vector_type(4))) float f32x4;

// ---------- frozen exact helpers ----------
__device__ __forceinline__ float sumsq_pairwise8(const float* x) {
    float r8[8];
    #pragma unroll
    for (int l = 0; l < 8; ++l) r8[l] = __fmul_rn(x[l], x[l]);
    #pragma unroll
    for (int i = 8; i < 64; i += 8)
        #pragma unroll
        for (int l = 0; l < 8; ++l)
            r8[l] = __fadd_rn(r8[l], __fmul_rn(x[i + l], x[i + l]));
    return __fadd_rn(__fadd_rn(__fadd_rn(r8[0], r8[1]), __fadd_rn(r8[2], r8[3])),
                     __fadd_rn(__fadd_rn(r8[4], r8[5]), __fadd_rn(r8[6], r8[7])));
}

__device__ __forceinline__ uint32_t bf16rn(float f) {
    union { float f; uint32_t u; } c; c.f = f;
    return (c.u + 0x7FFFu + ((c.u >> 16) & 1u)) >> 16;
}
__device__ __forceinline__ uint32_t pk2(float lo, float hi) {
    return bf16rn(lo) | (bf16rn(hi) << 16);
}

// ---------- phase 0a: f32 -> bf16 (RN) ----------
__global__ __launch_bounds__(256)
void vq_convert(const float* __restrict__ z, const float* __restrict__ e,
                uint32_t* __restrict__ zb, uint32_t* __restrict__ eb)
{
    const int i = blockIdx.x * 256 + threadIdx.x;
    const int nz = NROWS * D / 8;
    const int ne = NE * D / 8;
    if (i < nz) {
        const float4 a = ((const float4*)z)[i * 2];
        const float4 b = ((const float4*)z)[i * 2 + 1];
        uint4 o; o.x = pk2(a.x, a.y); o.y = pk2(a.z, a.w);
        o.z = pk2(b.x, b.y); o.w = pk2(b.z, b.w);
        ((uint4*)zb)[i] = o;
    } else if (i < nz + ne) {
        const int k = i - nz;
        const float4 a = ((const float4*)e)[k * 2];
        const float4 b = ((const float4*)e)[k * 2 + 1];
        uint4 o; o.x = pk2(a.x, a.y); o.y = pk2(a.z, a.w);
        o.z = pk2(b.x, b.y); o.w = pk2(b.z, b.w);
        ((uint4*)eb)[k] = o;
    }
}

// ---------- phase 0b: exact sz[row], se[j] ----------
__global__ __launch_bounds__(256)
void vq_prep(const float* __restrict__ z, const float* __restrict__ e,
             float* __restrict__ sz_arr, float* __restrict__ se_arr)
{
    const int i = blockIdx.x * 256 + threadIdx.x;
    const float* p;
    float* dst;
    if (i < NROWS) { p = z + (size_t)i * D; dst = sz_arr + i; }
    else if (i < NROWS + NE) { p = e + (size_t)(i - NROWS) * D; dst = se_arr + (i - NROWS); }
    else return;
    float x[D];
    #pragma unroll
    for (int k = 0; k < D; k += 4) {
        const float4 v = *(const float4*)(p + k);
        x[k] = v.x; x[k + 1] = v.y; x[k + 2] = v.z; x[k + 3] = v.w;
    }
    *dst = sumsq_pairwise8(x);
}

// ---------- phase 1: MFMA GEMM + per-(row,chunk) max (verified, unchanged) ----------
__global__ __launch_bounds__(256)
void vq_scan_mfma(const uint16_t* __restrict__ zb, const uint16_t* __restrict__ eb,
                  float* __restrict__ cmax)
{
    __shared__ uint16_t elds[BN][72];
    __shared__ float    rmld[4][64][20];

    const int tid  = threadIdx.x;
    const int lane = tid & 63, w = tid >> 6;
    const int mb   = blockIdx.x >> 5;
    const int jb   = blockIdx.x & 31;
    const int row0 = mb * 256 + w * 64;
    const int l15  = lane & 15, l4 = lane >> 4;

    short8 af[4][2];
    #pragma unroll
    for (int m = 0; m < 4; ++m)
        #pragma unroll
        for (int h = 0; h < 2; ++h)
            af[m][h] = *(const short8*)(zb + (size_t)(row0 + m * 16 + l15) * D + h * 32 + l4 * 8);

    const f32x4 z4 = {0.f, 0.f, 0.f, 0.f};

    #pragma unroll 1
    for (int c = 0; c < 2; ++c) {
        const int j0 = jb * 256 + c * BN;
        {
            const int srow = tid >> 1, shalf = tid & 1;
            const uint16_t* sp = eb + (size_t)(j0 + srow) * D + shalf * 32;
            uint16_t* dp = &elds[srow][shalf * 32];
            #pragma unroll
            for (int q = 0; q < 4; ++q)
                *(short8*)(dp + q * 8) = *(const short8*)(sp + q * 8);
        }
        __syncthreads();

        f32x4 rm[4];
        #pragma unroll
        for (int m = 0; m < 4; ++m) rm[m] = {-3.0e38f, -3.0e38f, -3.0e38f, -3.0e38f};

        #pragma unroll 1
        for (int n = 0; n < 8; ++n) {
            const uint16_t* bp = &elds[n * 16 + l15][l4 * 8];
            const short8 b0 = *(const short8*)(bp);
            const short8 b1 = *(const short8*)(bp + 32);
            #pragma unroll
            for (int m = 0; m < 4; ++m) {
                f32x4 acc = __builtin_amdgcn_mfma_f32_16x16x32_bf16(af[m][0], b0, z4, 0, 0, 0);
                acc = __builtin_amdgcn_mfma_f32_16x16x32_bf16(af[m][1], b1, acc, 0, 0, 0);
                #pragma unroll
                for (int r = 0; r < 4; ++r) rm[m][r] = fmaxf(rm[m][r], acc[r]);
            }
        }

        #pragma unroll
        for (int m = 0; m < 4; ++m)
            *(f32x4*)&rmld[w][lane][m * 4] = rm[m];
        const int r  = lane;
        const int mm = r >> 4, rg = r & 3, lg = ((r & 15) >> 2) * 16;
        float v = rmld[w][lg][mm * 4 + rg];
        #pragma unroll
        for (int i = 1; i < 16; ++i) v = fmaxf(v, rmld[w][lg + i][mm * 4 + rg]);
        cmax[(size_t)(row0 + r) * NCH + (jb * 2 + c)] = v;
        __syncthreads();
    }
}

// ---------- phase 2a: band-select -> per-row bitmask (NO atomics) ----------
__global__ __launch_bounds__(256)
void vq_select_mask(const float* __restrict__ cmax,
                    unsigned long long* __restrict__ mask,
                    unsigned long long* __restrict__ packed)
{
    const int lane = threadIdx.x & 63, w = threadIdx.x >> 6;
    const int row = blockIdx.x * 4 + w;

    const float ci = cmax[(size_t)row * NCH + lane];   // lane = chunk
    float cm = ci;
    #pragma unroll
    for (int o = 1; o < 64; o <<= 1) cm = fmaxf(cm, __shfl_xor(cm, o, 64));
    const unsigned long long m = __ballot(ci >= cm - BAND);
    if (lane == 0) { mask[row] = m; packed[row] = 0xFFFFFFFFFFFFFFFFull; }
}

// ---------- phase 2b: per-chunk ordered compaction (block scan, NO atomics) ----------
__global__ __launch_bounds__(256)
void vq_compact(const unsigned long long* __restrict__ mask,
                int* __restrict__ cand, unsigned int* __restrict__ counts)
{
    __shared__ unsigned int wsum[4];
    __shared__ unsigned int base;

    const int ch = blockIdx.x;                 // 0..63
    const int t = threadIdx.x, lane = t & 63, w = t >> 6;
    if (t == 0) base = 0;
    __syncthreads();

    for (int r0 = 0; r0 < NROWS; r0 += 256) {
        const int row = r0 + t;
        const bool hit = (mask[row] >> ch) & 1ull;
        const unsigned long long b = __ballot(hit);
        if (lane == 0) wsum[w] = (unsigned int)__popcll(b);
        __syncthreads();
        unsigned int pos = base;
        for (int i = 0; i < w; ++i) pos += wsum[i];
        if (hit) {
            pos += (unsigned int)__popcll(b & ((1ull << lane) - 1ull));
            cand[(size_t)ch * CAND_CAP + pos] = row;   // row-ascending order
        }
        __syncthreads();
        if (t == 0) base += wsum[0] + wsum[1] + wsum[2] + wsum[3];
        __syncthreads();
    }
    if (t == 0) counts[ch] = base;
}

// ---------- phase 2c: inverted exact eval (verified structure) ----------
__global__ __launch_bounds__(128, 2)
void vq_eval(const float* __restrict__ z, const float* __restrict__ e,
             const float* __restrict__ sz_arr, const float* __restrict__ se_arr,
             const unsigned int* __restrict__ counts, const int* __restrict__ cand,
             unsigned long long* __restrict__ packed)
{
    const int ch = blockIdx.x;           // 0..63
    const int jh = blockIdx.y;           // 0..1
    const int bb = blockIdx.z;           // 0..EVB-1
    const int t  = threadIdx.x;
    const unsigned int cnt = counts[ch];
    const int jbase = ch * BN + jh * 64;

    for (unsigned int s = bb * 128u + t; s < cnt; s += EVB * 128u) {
        const int row = cand[(size_t)ch * CAND_CAP + s];

        float zr[D];
        {
            const float* zp = z + (size_t)row * D;
            #pragma unroll
            for (int k = 0; k < D; k += 4) {
                const float4 v = *(const float4*)(zp + k);
                zr[k] = v.x; zr[k + 1] = v.y; zr[k + 2] = v.z; zr[k + 3] = v.w;
            }
        }
        const float sz = sz_arr[row];

        float bd = 3.0e38f; int bj = 0;
        #pragma unroll 1
        for (int jj = 0; jj < 64; ++jj) {
            const int j = jbase + jj;
            const float* er = e + (size_t)j * D;   // wave-uniform -> s_loads

            float q0 = 0.f, q1 = 0.f, q2 = 0.f, q3 = 0.f;
            #pragma unroll
            for (int cc = 0; cc < 4; ++cc) {
                #pragma unroll
                for (int sb = 3; sb >= 0; --sb) {
                    const int b = cc * 16 + sb * 4;
                    q0 = __fadd_rn(q0, __fmul_rn(zr[b + 0], er[b + 0]));
                    q1 = __fadd_rn(q1, __fmul_rn(zr[b + 1], er[b + 1]));
                    q2 = __fadd_rn(q2, __fmul_rn(zr[b + 2], er[b + 2]));
                    q3 = __fadd_rn(q3, __fmul_rn(zr[b + 3], er[b + 3]));
                }
            }
            const float c  = __fadd_rn(__fadd_rn(q0, q1), __fadd_rn(q2, q3));
            const float A  = __fadd_rn(sz, se_arr[j]);          // fl(sz + se)
            const float dd = __fsub_rn(A, __fadd_rn(c, c));     // fl(A - 2c)
            if (dd < bd) { bd = dd; bj = j; }                   // ascending j: first wins
        }
        const unsigned long long key =
            ((unsigned long long)__float_as_uint(bd) << 32) | (unsigned int)bj;
        atomicMin(packed + row, key);   // d>0 -> monotone bits; deterministic
    }
}

// ---------- phase 3: z_q + idx from packed ----------
__global__ __launch_bounds__(256)
void vq_zq(const float* __restrict__ z, const float* __restrict__ e,
           const unsigned long long* __restrict__ packed, float* __restrict__ out)
{
    const size_t m = (size_t)blockIdx.x * 256 + threadIdx.x;
    const int r = (int)(m >> 6), k = (int)(m & 63);
    const int sel = (int)(packed[r] & 0xFFFFFFFFull);
    const float zv = z[m];
    const float ev = e[(size_t)sel * D + k];
    out[m] = __fadd_rn(zv, __fsub_rn(ev, zv));
    if (k == 0) out[(size_t)NROWS * D + r] = (float)sel;
}

extern "C" void kernel_launch(void* const* d_in, const int* in_sizes, int n_in,
                              void* d_out, int out_size, void* d_ws, size_t ws_size,
                              hipStream_t stream)
{
    const float* z = (const float*)d_in[0];
    const float* e = (const float*)d_in[1];
    float* out = (float*)d_out;

    char* ws = (char*)d_ws;
    const size_t MB = 1024 * 1024, KB = 1024;
    uint16_t* zb               = (uint16_t*)(ws);                         // 0..2 MB
    uint16_t* eb               = (uint16_t*)(ws + 2 * MB);                // 2..3 MB
    float* cmaxb               = (float*)(ws + 3 * MB);                   // 3..7 MB
    float* sz_arr              = (float*)(ws + 7 * MB);                   // 64 KB
    float* se_arr              = (float*)(ws + 7 * MB + 64 * KB);         // 32 KB
    unsigned long long* mask   = (unsigned long long*)(ws + 7 * MB + 128 * KB); // 128 KB
    unsigned long long* packed = (unsigned long long*)(ws + 7 * MB + 256 * KB); // 128 KB
    unsigned int* counts       = (unsigned int*)(ws + 7 * MB + 384 * KB); // 256 B
    int* cand                  = (int*)(ws + 8 * MB);                     // 8..12 MB

    vq_convert    <<<dim3(768),                dim3(256), 0, stream>>>(z, e, (uint32_t*)zb, (uint32_t*)eb);
    vq_prep       <<<dim3((NROWS + NE) / 256), dim3(256), 0, stream>>>(z, e, sz_arr, se_arr);
    vq_scan_mfma  <<<dim3(2048),               dim3(256), 0, stream>>>(zb, eb, cmaxb);
    vq_select_mask<<<dim3(NROWS / 4),          dim3(256), 0, stream>>>(cmaxb, mask, packed);
    vq_compact    <<<dim3(NCH),                dim3(256), 0, stream>>>(mask, cand, counts);
    vq_eval       <<<dim3(NCH, 2, EVB),        dim3(128), 0, stream>>>(z, e, sz_arr, se_arr, counts, cand, packed);
    vq_zq         <<<dim3(NROWS * D / 256),    dim3(256), 0, stream>>>(z, e, packed, out);
}

// Round 12
// 119.767 us; speedup vs baseline: 1.9038x; 1.0520x over previous
//
#include <hip/hip_runtime.h>
#include <stdint.h>

// VectorQuantizer — f32 I/O confirmed. d_in[0]=z [16384,64], d_in[1]=e [8192,64];
// d_out f32: [z_q 16384*64][idx-as-float 16384]. d_ws >= 16MB confirmed.
//
// FROZEN exact numerics (eval path only):
//   sz,se: scalar pairwise-8; c: 4 lanes (k mod 4), mul/add separately rounded,
//   16-chunks ascending, reversed sub-blocks (+12,+8,+4,+0), hadd (q0+q1)+(q2+q3);
//   A=fl(sz+se); d=fl(A-2c); argmin strict-<, first (smallest) index wins.
//
// Round-12: (1) eval gets amdgpu_waves_per_eu(2,2) — round-11 showed VGPR=60
// (<64): launch_bounds only sets MIN waves, compiler still chased 8-wave
// occupancy and rematerialized zr loads. Clamping max=2 gives the 256-reg
// budget. (2) j split in quarters (JQ=4, 32j/slot, EVB=8) for ~4x working
// blocks (round-11 Occ 11%: only 4/16 bb blocks had work). (3) prep rewritten
// coalesced (wave per 8 rows, frozen-order shuffle tree) and fused w/ convert.

#define NROWS 16384
#define NE    8192
#define D     64
#define BN    128
#define NCH   (NE / BN)     // 64
#define BAND  1.25e-4f
#define CAND_CAP 16384
#define JQ    4             // j-quarters per chunk (32 j each)
#define EVB   8

typedef __attribute__((ext_vector_type(8))) short short8;
typedef __attribute__((ext_vector_type(4))) float f32x4;

__device__ __forceinline__ uint32_t bf16rn(float f) {
    union { float f; uint32_t u; } c; c.f = f;
    return (c.u + 0x7FFFu + ((c.u >> 16) & 1u)) >> 16;
}
__device__ __forceinline__ uint32_t pk2(float lo, float hi) {
    return bf16rn(lo) | (bf16rn(hi) << 16);
}

// ---------- phase 0: fused convert (blocks 0..767) + prep (blocks 768..1535) ----------
// prep: wave per 8 rows; lane sublane g owns k===g (mod 8). Frozen pairwise-8:
//   r8[g] = fl-chain of x[8i+g]^2 ascending i (per-lane);
//   tree via shfl_xor(1,2,4): lane g=0 computes fl(fl(fl(r0+r1)+fl(r2+r3)) +
//   fl(fl(r4+r5)+fl(r6+r7))) — bit-identical to the scalar helper.
__global__ __launch_bounds__(256)
void vq_convert_prep(const float* __restrict__ z, const float* __restrict__ e,
                     uint32_t* __restrict__ zb, uint32_t* __restrict__ eb,
                     float* __restrict__ sz_arr, float* __restrict__ se_arr)
{
    if (blockIdx.x < 768) {   // ---- convert: f32 -> bf16 RN, 8 floats/thread ----
        const int i = blockIdx.x * 256 + threadIdx.x;
        const int nz = NROWS * D / 8;
        const int ne = NE * D / 8;
        if (i < nz) {
            const float4 a = ((const float4*)z)[i * 2];
            const float4 b = ((const float4*)z)[i * 2 + 1];
            uint4 o; o.x = pk2(a.x, a.y); o.y = pk2(a.z, a.w);
            o.z = pk2(b.x, b.y); o.w = pk2(b.z, b.w);
            ((uint4*)zb)[i] = o;
        } else if (i < nz + ne) {
            const int k = i - nz;
            const float4 a = ((const float4*)e)[k * 2];
            const float4 b = ((const float4*)e)[k * 2 + 1];
            uint4 o; o.x = pk2(a.x, a.y); o.y = pk2(a.z, a.w);
            o.z = pk2(b.x, b.y); o.w = pk2(b.z, b.w);
            ((uint4*)eb)[k] = o;
        }
    } else {                  // ---- prep: exact sz/se, coalesced ----
        const int pb   = blockIdx.x - 768;
        const int wave = threadIdx.x >> 6, lane = threadIdx.x & 63;
        const int g    = lane & 7;                  // k mod 8 owner
        const int grow = pb * 32 + wave * 8 + (lane >> 3);   // 0..24575
        const float* src = (grow < NROWS) ? z + (size_t)grow * D
                                          : e + (size_t)(grow - NROWS) * D;
        float acc = 0.f;
        #pragma unroll
        for (int i = 0; i < 8; ++i) {
            const float x = src[i * 8 + g];
            acc = __fadd_rn(acc, __fmul_rn(x, x));
        }
        const float s1 = __fadd_rn(acc, __shfl_xor(acc, 1, 64));
        const float s2 = __fadd_rn(s1,  __shfl_xor(s1, 2, 64));
        const float s4 = __fadd_rn(s2,  __shfl_xor(s2, 4, 64));
        if (g == 0) {
            if (grow < NROWS) sz_arr[grow] = s4;
            else              se_arr[grow - NROWS] = s4;
        }
    }
}

// ---------- phase 1: MFMA GEMM + per-(row,chunk) max (verified, unchanged) ----------
__global__ __launch_bounds__(256)
void vq_scan_mfma(const uint16_t* __restrict__ zb, const uint16_t* __restrict__ eb,
                  float* __restrict__ cmax)
{
    __shared__ uint16_t elds[BN][72];
    __shared__ float    rmld[4][64][20];

    const int tid  = threadIdx.x;
    const int lane = tid & 63, w = tid >> 6;
    const int mb   = blockIdx.x >> 5;
    const int jb   = blockIdx.x & 31;
    const int row0 = mb * 256 + w * 64;
    const int l15  = lane & 15, l4 = lane >> 4;

    short8 af[4][2];
    #pragma unroll
    for (int m = 0; m < 4; ++m)
        #pragma unroll
        for (int h = 0; h < 2; ++h)
            af[m][h] = *(const short8*)(zb + (size_t)(row0 + m * 16 + l15) * D + h * 32 + l4 * 8);

    const f32x4 z4 = {0.f, 0.f, 0.f, 0.f};

    #pragma unroll 1
    for (int c = 0; c < 2; ++c) {
        const int j0 = jb * 256 + c * BN;
        {
            const int srow = tid >> 1, shalf = tid & 1;
            const uint16_t* sp = eb + (size_t)(j0 + srow) * D + shalf * 32;
            uint16_t* dp = &elds[srow][shalf * 32];
            #pragma unroll
            for (int q = 0; q < 4; ++q)
                *(short8*)(dp + q * 8) = *(const short8*)(sp + q * 8);
        }
        __syncthreads();

        f32x4 rm[4];
        #pragma unroll
        for (int m = 0; m < 4; ++m) rm[m] = {-3.0e38f, -3.0e38f, -3.0e38f, -3.0e38f};

        #pragma unroll 1
        for (int n = 0; n < 8; ++n) {
            const uint16_t* bp = &elds[n * 16 + l15][l4 * 8];
            const short8 b0 = *(const short8*)(bp);
            const short8 b1 = *(const short8*)(bp + 32);
            #pragma unroll
            for (int m = 0; m < 4; ++m) {
                f32x4 acc = __builtin_amdgcn_mfma_f32_16x16x32_bf16(af[m][0], b0, z4, 0, 0, 0);
                acc = __builtin_amdgcn_mfma_f32_16x16x32_bf16(af[m][1], b1, acc, 0, 0, 0);
                #pragma unroll
                for (int r = 0; r < 4; ++r) rm[m][r] = fmaxf(rm[m][r], acc[r]);
            }
        }

        #pragma unroll
        for (int m = 0; m < 4; ++m)
            *(f32x4*)&rmld[w][lane][m * 4] = rm[m];
        const int r  = lane;
        const int mm = r >> 4, rg = r & 3, lg = ((r & 15) >> 2) * 16;
        float v = rmld[w][lg][mm * 4 + rg];
        #pragma unroll
        for (int i = 1; i < 16; ++i) v = fmaxf(v, rmld[w][lg + i][mm * 4 + rg]);
        cmax[(size_t)(row0 + r) * NCH + (jb * 2 + c)] = v;
        __syncthreads();
    }
}

// ---------- phase 2a: band-select -> per-row bitmask (no atomics) ----------
__global__ __launch_bounds__(256)
void vq_select_mask(const float* __restrict__ cmax,
                    unsigned long long* __restrict__ mask,
                    unsigned long long* __restrict__ packed)
{
    const int lane = threadIdx.x & 63, w = threadIdx.x >> 6;
    const int row = blockIdx.x * 4 + w;

    const float ci = cmax[(size_t)row * NCH + lane];   // lane = chunk
    float cm = ci;
    #pragma unroll
    for (int o = 1; o < 64; o <<= 1) cm = fmaxf(cm, __shfl_xor(cm, o, 64));
    const unsigned long long m = __ballot(ci >= cm - BAND);
    if (lane == 0) { mask[row] = m; packed[row] = 0xFFFFFFFFFFFFFFFFull; }
}

// ---------- phase 2b: per-chunk ordered compaction (block scan, no atomics) ----------
__global__ __launch_bounds__(256)
void vq_compact(const unsigned long long* __restrict__ mask,
                int* __restrict__ cand, unsigned int* __restrict__ counts)
{
    __shared__ unsigned int wsum[4];
    __shared__ unsigned int base;

    const int ch = blockIdx.x;
    const int t = threadIdx.x, lane = t & 63, w = t >> 6;
    if (t == 0) base = 0;
    __syncthreads();

    for (int r0 = 0; r0 < NROWS; r0 += 256) {
        const int row = r0 + t;
        const bool hit = (mask[row] >> ch) & 1ull;
        const unsigned long long b = __ballot(hit);
        if (lane == 0) wsum[w] = (unsigned int)__popcll(b);
        __syncthreads();
        unsigned int pos = base;
        for (int i = 0; i < w; ++i) pos += wsum[i];
        if (hit) {
            pos += (unsigned int)__popcll(b & ((1ull << lane) - 1ull));
            cand[(size_t)ch * CAND_CAP + pos] = row;   // row-ascending
        }
        __syncthreads();
        if (t == 0) base += wsum[0] + wsum[1] + wsum[2] + wsum[3];
        __syncthreads();
    }
    if (t == 0) counts[ch] = base;
}

// ---------- phase 2c: inverted exact eval (j-quarters; forced 2-wave/EU) ----------
__global__ __launch_bounds__(128)
__attribute__((amdgpu_waves_per_eu(2, 2)))
void vq_eval(const float* __restrict__ z, const float* __restrict__ e,
             const float* __restrict__ sz_arr, const float* __restrict__ se_arr,
             const unsigned int* __restrict__ counts, const int* __restrict__ cand,
             unsigned long long* __restrict__ packed)
{
    const int ch = blockIdx.x;           // 0..63
    const int q  = blockIdx.y;           // 0..JQ-1
    const int bb = blockIdx.z;           // 0..EVB-1
    const int t  = threadIdx.x;
    const unsigned int cnt = counts[ch];
    const int jbase = ch * BN + q * (BN / JQ);

    for (unsigned int s = bb * 128u + t; s < cnt; s += EVB * 128u) {
        const int row = cand[(size_t)ch * CAND_CAP + s];

        float zr[D];
        {
            const float* zp = z + (size_t)row * D;
            #pragma unroll
            for (int k = 0; k < D; k += 4) {
                const float4 v = *(const float4*)(zp + k);
                zr[k] = v.x; zr[k + 1] = v.y; zr[k + 2] = v.z; zr[k + 3] = v.w;
            }
        }
        const float sz = sz_arr[row];

        float bd = 3.0e38f; int bj = 0;
        #pragma unroll 1
        for (int jj = 0; jj < BN / JQ; ++jj) {
            const int j = jbase + jj;
            const float* er = e + (size_t)j * D;   // wave-uniform -> s_loads

            float q0 = 0.f, q1 = 0.f, q2 = 0.f, q3 = 0.f;
            #pragma unroll
            for (int cc = 0; cc < 4; ++cc) {
                #pragma unroll
                for (int sb = 3; sb >= 0; --sb) {
                    const int b = cc * 16 + sb * 4;
                    q0 = __fadd_rn(q0, __fmul_rn(zr[b + 0], er[b + 0]));
                    q1 = __fadd_rn(q1, __fmul_rn(zr[b + 1], er[b + 1]));
                    q2 = __fadd_rn(q2, __fmul_rn(zr[b + 2], er[b + 2]));
                    q3 = __fadd_rn(q3, __fmul_rn(zr[b + 3], er[b + 3]));
                }
            }
            const float c  = __fadd_rn(__fadd_rn(q0, q1), __fadd_rn(q2, q3));
            const float A  = __fadd_rn(sz, se_arr[j]);          // fl(sz + se)
            const float dd = __fsub_rn(A, __fadd_rn(c, c));     // fl(A - 2c)
            if (dd < bd) { bd = dd; bj = j; }                   // ascending j: first wins
        }
        const unsigned long long key =
            ((unsigned long long)__float_as_uint(bd) << 32) | (unsigned int)bj;
        atomicMin(packed + row, key);   // d>0 -> monotone bits; deterministic
    }
}

// ---------- phase 3: z_q + idx from packed ----------
__global__ __launch_bounds__(256)
void vq_zq(const float* __restrict__ z, const float* __restrict__ e,
           const unsigned long long* __restrict__ packed, float* __restrict__ out)
{
    const size_t m = (size_t)blockIdx.x * 256 + threadIdx.x;
    const int r = (int)(m >> 6), k = (int)(m & 63);
    const int sel = (int)(packed[r] & 0xFFFFFFFFull);
    const float zv = z[m];
    const float ev = e[(size_t)sel * D + k];
    out[m] = __fadd_rn(zv, __fsub_rn(ev, zv));
    if (k == 0) out[(size_t)NROWS * D + r] = (float)sel;
}

extern "C" void kernel_launch(void* const* d_in, const int* in_sizes, int n_in,
                              void* d_out, int out_size, void* d_ws, size_t ws_size,
                              hipStream_t stream)
{
    const float* z = (const float*)d_in[0];
    const float* e = (const float*)d_in[1];
    float* out = (float*)d_out;

    char* ws = (char*)d_ws;
    const size_t MB = 1024 * 1024, KB = 1024;
    uint16_t* zb               = (uint16_t*)(ws);                         // 0..2 MB
    uint16_t* eb               = (uint16_t*)(ws + 2 * MB);                // 2..3 MB
    float* cmaxb               = (float*)(ws + 3 * MB);                   // 3..7 MB
    float* sz_arr              = (float*)(ws + 7 * MB);                   // 64 KB
    float* se_arr              = (float*)(ws + 7 * MB + 64 * KB);         // 32 KB
    unsigned long long* mask   = (unsigned long long*)(ws + 7 * MB + 128 * KB); // 128 KB
    unsigned long long* packed = (unsigned long long*)(ws + 7 * MB + 256 * KB); // 128 KB
    unsigned int* counts       = (unsigned int*)(ws + 7 * MB + 384 * KB); // 256 B
    int* cand                  = (int*)(ws + 8 * MB);                     // 8..12 MB

    vq_convert_prep<<<dim3(1536),            dim3(256), 0, stream>>>(z, e, (uint32_t*)zb, (uint32_t*)eb, sz_arr, se_arr);
    vq_scan_mfma   <<<dim3(2048),            dim3(256), 0, stream>>>(zb, eb, cmaxb);
    vq_select_mask <<<dim3(NROWS / 4),       dim3(256), 0, stream>>>(cmaxb, mask, packed);
    vq_compact     <<<dim3(NCH),             dim3(256), 0, stream>>>(mask, cand, counts);
    vq_eval        <<<dim3(NCH, JQ, EVB),    dim3(128), 0, stream>>>(z, e, sz_arr, se_arr, counts, cand, packed);
    vq_zq          <<<dim3(NROWS * D / 256), dim3(256), 0, stream>>>(z, e, packed, out);
}

// Round 13
// 115.094 us; speedup vs baseline: 1.9811x; 1.0406x over previous
//
#include <hip/hip_runtime.h>
#include <stdint.h>

// VectorQuantizer — f32 I/O confirmed. d_in[0]=z [16384,64], d_in[1]=e [8192,64];
// d_out f32: [z_q 16384*64][idx-as-float 16384]. d_ws >= 16MB confirmed.
//
// FROZEN exact numerics (eval path only):
//   sz,se: scalar pairwise-8; c: 4 lanes (k mod 4), mul/add separately rounded,
//   16-chunks ascending, reversed sub-blocks (+12,+8,+4,+0), hadd (q0+q1)+(q2+q3);
//   A=fl(sz+se); d=fl(A-2c); argmin strict-<, first (smallest) index wins.
//
// Round-13: eval was L2-BOUND: 26K items x 32KB e-chunk s_load re-reads = 830MB
// of redundant L2 traffic (~24us at 35TB/s) — that's why no register/occupancy
// knob moved it. Eval v4: block=(chunk,group) stages the chunk's contiguous
// 32KB e-tile in LDS ONCE (coalesced), items of that chunk eval against it;
// j-loop is thread-uniform -> every LDS e-read is a broadcast (conflict-free).
// e-traffic 830MB -> 16MB. Compact v2: order is irrelevant (atomicMin combine
// is order-invariant) -> barrier-free per-wave ballot + LDS atomicAdd.

#define NROWS 16384
#define NE    8192
#define D     64
#define BN    128
#define NCH   (NE / BN)     // 64
#define BAND  1.25e-4f
#define CAND_CAP 16384
#define EVG   8             // eval groups per chunk

typedef __attribute__((ext_vector_type(8))) short short8;
typedef __attribute__((ext_vector_type(4))) float f32x4;

__device__ __forceinline__ uint32_t bf16rn(float f) {
    union { float f; uint32_t u; } c; c.f = f;
    return (c.u + 0x7FFFu + ((c.u >> 16) & 1u)) >> 16;
}
__device__ __forceinline__ uint32_t pk2(float lo, float hi) {
    return bf16rn(lo) | (bf16rn(hi) << 16);
}

// ---------- phase 0: fused convert + coalesced exact prep (verified r12) ----------
__global__ __launch_bounds__(256)
void vq_convert_prep(const float* __restrict__ z, const float* __restrict__ e,
                     uint32_t* __restrict__ zb, uint32_t* __restrict__ eb,
                     float* __restrict__ sz_arr, float* __restrict__ se_arr)
{
    if (blockIdx.x < 768) {
        const int i = blockIdx.x * 256 + threadIdx.x;
        const int nz = NROWS * D / 8;
        const int ne = NE * D / 8;
        if (i < nz) {
            const float4 a = ((const float4*)z)[i * 2];
            const float4 b = ((const float4*)z)[i * 2 + 1];
            uint4 o; o.x = pk2(a.x, a.y); o.y = pk2(a.z, a.w);
            o.z = pk2(b.x, b.y); o.w = pk2(b.z, b.w);
            ((uint4*)zb)[i] = o;
        } else if (i < nz + ne) {
            const int k = i - nz;
            const float4 a = ((const float4*)e)[k * 2];
            const float4 b = ((const float4*)e)[k * 2 + 1];
            uint4 o; o.x = pk2(a.x, a.y); o.y = pk2(a.z, a.w);
            o.z = pk2(b.x, b.y); o.w = pk2(b.z, b.w);
            ((uint4*)eb)[k] = o;
        }
    } else {
        const int pb   = blockIdx.x - 768;
        const int wave = threadIdx.x >> 6, lane = threadIdx.x & 63;
        const int g    = lane & 7;
        const int grow = pb * 32 + wave * 8 + (lane >> 3);
        const float* src = (grow < NROWS) ? z + (size_t)grow * D
                                          : e + (size_t)(grow - NROWS) * D;
        float acc = 0.f;
        #pragma unroll
        for (int i = 0; i < 8; ++i) {
            const float x = src[i * 8 + g];
            acc = __fadd_rn(acc, __fmul_rn(x, x));
        }
        const float s1 = __fadd_rn(acc, __shfl_xor(acc, 1, 64));
        const float s2 = __fadd_rn(s1,  __shfl_xor(s1, 2, 64));
        const float s4 = __fadd_rn(s2,  __shfl_xor(s2, 4, 64));
        if (g == 0) {
            if (grow < NROWS) sz_arr[grow] = s4;
            else              se_arr[grow - NROWS] = s4;
        }
    }
}

// ---------- phase 1: MFMA GEMM + per-(row,chunk) max (verified, unchanged) ----------
__global__ __launch_bounds__(256)
void vq_scan_mfma(const uint16_t* __restrict__ zb, const uint16_t* __restrict__ eb,
                  float* __restrict__ cmax)
{
    __shared__ uint16_t elds[BN][72];
    __shared__ float    rmld[4][64][20];

    const int tid  = threadIdx.x;
    const int lane = tid & 63, w = tid >> 6;
    const int mb   = blockIdx.x >> 5;
    const int jb   = blockIdx.x & 31;
    const int row0 = mb * 256 + w * 64;
    const int l15  = lane & 15, l4 = lane >> 4;

    short8 af[4][2];
    #pragma unroll
    for (int m = 0; m < 4; ++m)
        #pragma unroll
        for (int h = 0; h < 2; ++h)
            af[m][h] = *(const short8*)(zb + (size_t)(row0 + m * 16 + l15) * D + h * 32 + l4 * 8);

    const f32x4 z4 = {0.f, 0.f, 0.f, 0.f};

    #pragma unroll 1
    for (int c = 0; c < 2; ++c) {
        const int j0 = jb * 256 + c * BN;
        {
            const int srow = tid >> 1, shalf = tid & 1;
            const uint16_t* sp = eb + (size_t)(j0 + srow) * D + shalf * 32;
            uint16_t* dp = &elds[srow][shalf * 32];
            #pragma unroll
            for (int q = 0; q < 4; ++q)
                *(short8*)(dp + q * 8) = *(const short8*)(sp + q * 8);
        }
        __syncthreads();

        f32x4 rm[4];
        #pragma unroll
        for (int m = 0; m < 4; ++m) rm[m] = {-3.0e38f, -3.0e38f, -3.0e38f, -3.0e38f};

        #pragma unroll 1
        for (int n = 0; n < 8; ++n) {
            const uint16_t* bp = &elds[n * 16 + l15][l4 * 8];
            const short8 b0 = *(const short8*)(bp);
            const short8 b1 = *(const short8*)(bp + 32);
            #pragma unroll
            for (int m = 0; m < 4; ++m) {
                f32x4 acc = __builtin_amdgcn_mfma_f32_16x16x32_bf16(af[m][0], b0, z4, 0, 0, 0);
                acc = __builtin_amdgcn_mfma_f32_16x16x32_bf16(af[m][1], b1, acc, 0, 0, 0);
                #pragma unroll
                for (int r = 0; r < 4; ++r) rm[m][r] = fmaxf(rm[m][r], acc[r]);
            }
        }

        #pragma unroll
        for (int m = 0; m < 4; ++m)
            *(f32x4*)&rmld[w][lane][m * 4] = rm[m];
        const int r  = lane;
        const int mm = r >> 4, rg = r & 3, lg = ((r & 15) >> 2) * 16;
        float v = rmld[w][lg][mm * 4 + rg];
        #pragma unroll
        for (int i = 1; i < 16; ++i) v = fmaxf(v, rmld[w][lg + i][mm * 4 + rg]);
        cmax[(size_t)(row0 + r) * NCH + (jb * 2 + c)] = v;
        __syncthreads();
    }
}

// ---------- phase 2a: band-select -> per-row bitmask (no atomics) ----------
__global__ __launch_bounds__(256)
void vq_select_mask(const float* __restrict__ cmax,
                    unsigned long long* __restrict__ mask,
                    unsigned long long* __restrict__ packed)
{
    const int lane = threadIdx.x & 63, w = threadIdx.x >> 6;
    const int row = blockIdx.x * 4 + w;

    const float ci = cmax[(size_t)row * NCH + lane];   // lane = chunk
    float cm = ci;
    #pragma unroll
    for (int o = 1; o < 64; o <<= 1) cm = fmaxf(cm, __shfl_xor(cm, o, 64));
    const unsigned long long m = __ballot(ci >= cm - BAND);
    if (lane == 0) { mask[row] = m; packed[row] = 0xFFFFFFFFFFFFFFFFull; }
}

// ---------- phase 2b: compaction v2 — barrier-free, LDS atomic, unordered ----------
// (order irrelevant: eval combines via order-invariant atomicMin)
__global__ __launch_bounds__(256)
void vq_compact(const unsigned long long* __restrict__ mask,
                int* __restrict__ cand, unsigned int* __restrict__ counts)
{
    __shared__ unsigned int cnt_lds;
    const int ch = blockIdx.x;
    const int t = threadIdx.x, lane = t & 63;
    if (t == 0) cnt_lds = 0;
    __syncthreads();

    #pragma unroll 1
    for (int r0 = 0; r0 < NROWS; r0 += 256) {
        const int row = r0 + t;
        const bool hit = (mask[row] >> ch) & 1ull;
        const unsigned long long b = __ballot(hit);
        unsigned int base = 0;
        if (lane == 0 && b) base = atomicAdd(&cnt_lds, (unsigned int)__popcll(b));
        base = (unsigned int)__shfl((int)base, 0, 64);
        if (hit) {
            const unsigned int rank = (unsigned int)__popcll(b & ((1ull << lane) - 1ull));
            cand[(size_t)ch * CAND_CAP + base + rank] = row;
        }
    }
    __syncthreads();
    if (t == 0) counts[ch] = cnt_lds;
}

// ---------- phase 2c: eval v4 — LDS-staged e-chunk, broadcast reads ----------
__global__ __launch_bounds__(128)
__attribute__((amdgpu_waves_per_eu(2, 2)))
void vq_eval(const float* __restrict__ z, const float* __restrict__ e,
             const float* __restrict__ sz_arr, const float* __restrict__ se_arr,
             const unsigned int* __restrict__ counts, const int* __restrict__ cand,
             unsigned long long* __restrict__ packed)
{
    __shared__ float el[BN][D];                  // 32 KB, contiguous chunk tile

    const int ch = blockIdx.x;                   // 0..63
    const int g  = blockIdx.y;                   // 0..EVG-1
    const int t  = threadIdx.x;

    {   // stage: chunk = 128 consecutive e-rows = 32 KB contiguous, coalesced
        const float4* src = (const float4*)(e + (size_t)ch * BN * D);
        float4* dst = (float4*)&el[0][0];
        #pragma unroll
        for (int v = 0; v < BN * D / 4 / 128; ++v)
            dst[v * 128 + t] = src[v * 128 + t];
    }
    __syncthreads();

    const unsigned int cnt = counts[ch];
    const int jbase = ch * BN;
    const float* __restrict__ se_ch = se_arr + jbase;

    for (unsigned int s = (unsigned int)g * 128u + t; s < cnt; s += EVG * 128u) {
        const int row = cand[(size_t)ch * CAND_CAP + s];

        float zr[D];
        {
            const float* zp = z + (size_t)row * D;
            #pragma unroll
            for (int k = 0; k < D; k += 4) {
                const float4 v = *(const float4*)(zp + k);
                zr[k] = v.x; zr[k + 1] = v.y; zr[k + 2] = v.z; zr[k + 3] = v.w;
            }
        }
        const float sz = sz_arr[row];

        float bd = 3.0e38f; int bj = 0;
        #pragma unroll 1
        for (int jj = 0; jj < BN; ++jj) {
            // frozen order: cc ascending; granules +12,+8,+4,+0; q_i gets k===i mod 4.
            // el reads are thread-uniform -> LDS broadcast (conflict-free).
            float q0 = 0.f, q1 = 0.f, q2 = 0.f, q3 = 0.f;
            #pragma unroll
            for (int cc = 0; cc < 4; ++cc) {
                #pragma unroll
                for (int sb = 3; sb >= 0; --sb) {
                    const int b = cc * 16 + sb * 4;
                    const float4 ev = *(const float4*)&el[jj][b];
                    q0 = __fadd_rn(q0, __fmul_rn(zr[b + 0], ev.x));
                    q1 = __fadd_rn(q1, __fmul_rn(zr[b + 1], ev.y));
                    q2 = __fadd_rn(q2, __fmul_rn(zr[b + 2], ev.z));
                    q3 = __fadd_rn(q3, __fmul_rn(zr[b + 3], ev.w));
                }
            }
            const float c  = __fadd_rn(__fadd_rn(q0, q1), __fadd_rn(q2, q3));
            const float A  = __fadd_rn(sz, se_ch[jj]);          // fl(sz + se)
            const float dd = __fsub_rn(A, __fadd_rn(c, c));     // fl(A - 2c)
            if (dd < bd) { bd = dd; bj = jbase + jj; }          // ascending j: first wins
        }
        const unsigned long long key =
            ((unsigned long long)__float_as_uint(bd) << 32) | (unsigned int)bj;
        atomicMin(packed + row, key);   // d>0 -> monotone bits; deterministic
    }
}

// ---------- phase 3: z_q + idx from packed ----------
__global__ __launch_bounds__(256)
void vq_zq(const float* __restrict__ z, const float* __restrict__ e,
           const unsigned long long* __restrict__ packed, float* __restrict__ out)
{
    const size_t m = (size_t)blockIdx.x * 256 + threadIdx.x;
    const int r = (int)(m >> 6), k = (int)(m & 63);
    const int sel = (int)(packed[r] & 0xFFFFFFFFull);
    const float zv = z[m];
    const float ev = e[(size_t)sel * D + k];
    out[m] = __fadd_rn(zv, __fsub_rn(ev, zv));
    if (k == 0) out[(size_t)NROWS * D + r] = (float)sel;
}

extern "C" void kernel_launch(void* const* d_in, const int* in_sizes, int n_in,
                              void* d_out, int out_size, void* d_ws, size_t ws_size,
                              hipStream_t stream)
{
    const float* z = (const float*)d_in[0];
    const float* e = (const float*)d_in[1];
    float* out = (float*)d_out;

    char* ws = (char*)d_ws;
    const size_t MB = 1024 * 1024, KB = 1024;
    uint16_t* zb               = (uint16_t*)(ws);                         // 0..2 MB
    uint16_t* eb               = (uint16_t*)(ws + 2 * MB);                // 2..3 MB
    float* cmaxb               = (float*)(ws + 3 * MB);                   // 3..7 MB
    float* sz_arr              = (float*)(ws + 7 * MB);                   // 64 KB
    float* se_arr              = (float*)(ws + 7 * MB + 64 * KB);         // 32 KB
    unsigned long long* mask   = (unsigned long long*)(ws + 7 * MB + 128 * KB); // 128 KB
    unsigned long long* packed = (unsigned long long*)(ws + 7 * MB + 256 * KB); // 128 KB
    unsigned int* counts       = (unsigned int*)(ws + 7 * MB + 384 * KB); // 256 B
    int* cand                  = (int*)(ws + 8 * MB);                     // 8..12 MB

    vq_convert_prep<<<dim3(1536),            dim3(256), 0, stream>>>(z, e, (uint32_t*)zb, (uint32_t*)eb, sz_arr, se_arr);
    vq_scan_mfma   <<<dim3(2048),            dim3(256), 0, stream>>>(zb, eb, cmaxb);
    vq_select_mask <<<dim3(NROWS / 4),       dim3(256), 0, stream>>>(cmaxb, mask, packed);
    vq_compact     <<<dim3(NCH),             dim3(256), 0, stream>>>(mask, cand, counts);
    vq_eval        <<<dim3(NCH, EVG),        dim3(128), 0, stream>>>(z, e, sz_arr, se_arr, counts, cand, packed);
    vq_zq          <<<dim3(NROWS * D / 256), dim3(256), 0, stream>>>(z, e, packed, out);
}